// Round 13
// baseline (1314.953 us; speedup 1.0000x reference)
//
#include <hip/hip_runtime.h>

#define NB 112
#define SEQ 128
#define DM 768
#define NH 12
#define HD 64
#define FF 3072
#define NLAYER 3
#define MTOK (NB*SEQ)            // 14336
#define QKVN (3*DM)              // 2304
#define HEADTOT (NB*NH)          // 1344
#define QSZ ((size_t)HEADTOT*SEQ*HD)   // 11010048 elems per q/k/v

typedef unsigned short u16;
typedef __attribute__((ext_vector_type(8))) short short8;
typedef __attribute__((ext_vector_type(4))) float f32x4;
typedef __attribute__((ext_vector_type(4))) unsigned short us4;

__device__ __forceinline__ u16 f2bf(float f){
  unsigned u = __builtin_bit_cast(unsigned, f);
  u += 0x7FFFu + ((u >> 16) & 1u);
  return (u16)(u >> 16);
}
__device__ __forceinline__ float bf2f(u16 b){
  unsigned u = ((unsigned)b) << 16;
  return __builtin_bit_cast(float, u);
}
// packed RNE f32x2 -> bf16x2 (lo=s0, hi=s1)
__device__ __forceinline__ unsigned cvt_pk_bf16(float lo, float hi){
  unsigned r;
  asm("v_cvt_pk_bf16_f32 %0, %1, %2" : "=v"(r) : "v"(lo), "v"(hi));
  return r;
}
// tanh-GELU in sigmoid form: 0.5x(1+tanh(z)) == x / (1 + e^{-2z})
__device__ __forceinline__ float gelu_t(float x){
  const float t = -1.5957691216057308f * x * __builtin_fmaf(0.044715f, x*x, 1.0f);
  return __fdividef(x, 1.0f + __expf(t));
}

__device__ __forceinline__ void gl_lds16(const void* g, void* l){
  __builtin_amdgcn_global_load_lds((const __attribute__((address_space(1))) unsigned*)g,
                                   (__attribute__((address_space(3))) unsigned*)l, 16, 0, 0);
}

// ========== persistent 128x128 GEMM, BK=32, 3 blocks/CU (m97-class) =========
// C[m,n] = sum_k A[m,k]*W[n,k]. 256 thr = 4 waves (2M x 2N), wave tile 64x64.
// acc = 64 AGPR + ~90 VGPR -> 3 blocks/CU (independent barriers = implicit
// cross-block latency hiding, the lever the 256^2 tile could not reach).
// LDS 32KB: 2 buf x (A 128x32 + B 128x32) bf16, 64B rows.
// Swizzle: slot s (16B) of row r holds k-chunk s^(r&3); staged linearly with
// pre-swizzled global source, read with matching XOR (G21 both-sides rule).
// Depth-2 counted pipeline, 2 barriers/iter:
//   read frags(buf); lgkm0; barrier; stage(buf, t+2); MFMA;
//   vmcnt(4)[leaves t+2 in flight]; barrier.
// grid = 672 for ALL shapes (QKV tpb3, FFN1 tpb4, O/FFN2 tpb1) -> no idle CUs.
// EPI: 1 = gelu(acc+bias)->bf16 ; 2 = y=acc+bias+res(bf16) -> f32 + BN partials ;
//      3 = qkv head-scatter bf16
template<int EPI>
__global__ __launch_bounds__(256, 3)
void gemm_bt(const u16* __restrict__ A, const u16* __restrict__ W,
             const float* __restrict__ bias, u16* __restrict__ obf,
             float* __restrict__ of32, const u16* __restrict__ res,
             float* __restrict__ p1, float* __restrict__ p2,
             int M, int N, int K, int Nt, int TPB)
{
  __shared__ __align__(16) char smem[32768];
  const int tid = threadIdx.x;
  const int w = tid >> 6, lane = tid & 63;
  const int wm = w >> 1, wn = w & 1;
  const int fr = lane & 15, fg = lane >> 4;
  // XCD-chunked bijective swizzle (grid 672 % 8 == 0)
  const int grid = gridDim.x;
  const int q8 = grid >> 3;
  const int xcd = blockIdx.x & 7, pos = blockIdx.x >> 3;
  const int swz = xcd * q8 + pos;
  const int nt = K >> 5;                 // BK = 32
  const int tot = TPB * nt;
  // staging: thread t covers row t>>2, slot t&3, holding k-chunk (t&3)^(row&3)
  const int rowt = tid >> 2;
  const int kofs = ((tid & 3) ^ (rowt & 3)) * 8;
  auto stage = [&](int bb, int bm_, int bn_, int kt_) {
    const int kbase = kt_ * 32 + kofs;
    #pragma unroll
    for (int j = 0; j < 2; j++) {
      const u16* ga = A + (size_t)(bm_ + j*64 + rowt) * K + kbase;
      gl_lds16(ga, smem + bb*16384 + j*4096 + tid*16);
    }
    #pragma unroll
    for (int j = 0; j < 2; j++) {
      const u16* gb = W + (size_t)(bn_ + j*64 + rowt) * K + kbase;
      gl_lds16(gb, smem + bb*16384 + 8192 + j*4096 + tid*16);
    }
  };
  auto rdA = [&](int bb, int mf) -> short8 {
    const int row = wm*64 + mf*16 + fr;
    return *(const short8*)(smem + bb*16384 + row*64 + ((fg ^ (row & 3)) * 16));
  };
  auto rdB = [&](int bb, int nf) -> short8 {
    const int row = wn*64 + nf*16 + fr;
    return *(const short8*)(smem + bb*16384 + 8192 + row*64 + ((fg ^ (row & 3)) * 16));
  };
  auto coord = [&](int r, int& bm, int& bn) {
    const int lin = swz * TPB + r;
    const int mI = lin / Nt;
    bm = mI * 128; bn = (lin - mI * Nt) * 128;
  };

  f32x4 acc[4][4] = {};

  auto epi = [&](int bm, int bn) {
    float bs[4] = {0,0,0,0}, bq[4] = {0,0,0,0};
    #pragma unroll
    for (int ni = 0; ni < 4; ni++) {
      const int c = bn + wn*64 + ni*16 + fr;
      const float bc = bias[c];
      #pragma unroll
      for (int mi = 0; mi < 4; mi++) {
        const int r0 = bm + wm*64 + mi*16 + fg*4;
        float v[4];
        #pragma unroll
        for (int j = 0; j < 4; j++) v[j] = acc[mi][ni][j] + bc;
        if constexpr (EPI == 1) {
          #pragma unroll
          for (int j = 0; j < 4; j++) v[j] = gelu_t(v[j]);
          const unsigned p01 = cvt_pk_bf16(v[0], v[1]);
          const unsigned p23 = cvt_pk_bf16(v[2], v[3]);
          u16* d = obf + (size_t)r0 * N + c;
          d[0] = (u16)p01; d[N] = (u16)(p01 >> 16);
          d[2*N] = (u16)p23; d[3*N] = (u16)(p23 >> 16);
        } else if constexpr (EPI == 2) {
          #pragma unroll
          for (int j = 0; j < 4; j++) {
            const float y = v[j] + bf2f(res[(size_t)(r0+j) * N + c]);
            of32[(size_t)(r0+j) * N + c] = y;
            bs[ni] += y; bq[ni] += y * y;
          }
        } else {
          const int which = c / DM;
          const int cc = c - which * DM;
          const int hh = cc >> 6, e = cc & 63;
          const int bb = r0 >> 7, l = r0 & 127;
          const unsigned p01 = cvt_pk_bf16(v[0], v[1]);
          const unsigned p23 = cvt_pk_bf16(v[2], v[3]);
          u16* d = obf + (size_t)which * QSZ + ((size_t)(bb*NH + hh) * SEQ + l) * HD + e;
          d[0] = (u16)p01; d[HD] = (u16)(p01 >> 16);
          d[2*HD] = (u16)p23; d[3*HD] = (u16)(p23 >> 16);
        }
        acc[mi][ni] = (f32x4){0.f, 0.f, 0.f, 0.f};
      }
    }
    if constexpr (EPI == 2) {
      const int mIdx = bm >> 7;            // 112 m-tiles -> 224 p-rows
      #pragma unroll
      for (int ni = 0; ni < 4; ni++) {
        float s = bs[ni], qq = bq[ni];
        s  += __shfl_xor(s, 16);  s  += __shfl_xor(s, 32);
        qq += __shfl_xor(qq, 16); qq += __shfl_xor(qq, 32);
        if (fg == 0) {
          const int c = bn + wn*64 + ni*16 + fr;
          p1[(mIdx*2 + wm) * N + c] = s;
          p2[(mIdx*2 + wm) * N + c] = qq;
        }
      }
    }
  };

  // trackers: t (epilogue) and t+2 (staging)
  int r0t = 0, kt0 = 0, bm0, bn0; coord(0, bm0, bn0);
  int r2 = 0, kt2 = 2, bm2 = bm0, bn2 = bn0;   // nt >= 24 so t+2 is in tile 0

  stage(0, bm0, bn0, 0);
  stage(1, bm0, bn0, 1);
  asm volatile("s_waitcnt vmcnt(4)" ::: "memory");
  __builtin_amdgcn_s_barrier();

  short8 a[4], b[4];
  for (int t = 0; t < tot; ++t) {
    const int buf = t & 1;
    const bool st1 = (t + 1 < tot), st2 = (t + 2 < tot);
    #pragma unroll
    for (int i = 0; i < 4; i++) a[i] = rdA(buf, i);
    #pragma unroll
    for (int i = 0; i < 4; i++) b[i] = rdB(buf, i);
    asm volatile("s_waitcnt lgkmcnt(0)" ::: "memory");
    __builtin_amdgcn_sched_barrier(0);
    __builtin_amdgcn_s_barrier();              // all waves' reads landed
    if (st2) stage(buf, bm2, bn2, kt2);        // overwrite current buf for t+2
    __builtin_amdgcn_s_setprio(1);
    #pragma unroll
    for (int mi = 0; mi < 4; mi++)
      #pragma unroll
      for (int ni = 0; ni < 4; ni++)
        acc[mi][ni] = __builtin_amdgcn_mfma_f32_16x16x32_bf16(a[mi], b[ni], acc[mi][ni], 0, 0, 0);
    __builtin_amdgcn_s_setprio(0);
    if (st2)      { asm volatile("s_waitcnt vmcnt(4)" ::: "memory"); }  // drain t+1
    else if (st1) { asm volatile("s_waitcnt vmcnt(0)" ::: "memory"); }
    __builtin_amdgcn_s_barrier();
    if (kt0 == nt - 1) {
      epi(bm0, bn0);
      kt0 = 0; r0t++;
      if (r0t < TPB) coord(r0t, bm0, bn0);
    } else kt0++;
    kt2++; if (kt2 == nt) { kt2 = 0; r2++; if (r2 < TPB) coord(r2, bm2, bn2); }
  }
}

// ---------------- Attention: one block per (b,h) -----------------------------
__global__ __launch_bounds__(256)
void attn_kernel(const u16* __restrict__ qkvb, const u16* __restrict__ biasT,
                 u16* __restrict__ ab)
{
  const int h = blockIdx.x, b = blockIdx.y;
  const int tid = threadIdx.x, w = tid >> 6, lane = tid & 63;
  const int bh = b * NH + h;
  const u16* qp = qkvb + (size_t)bh * SEQ * HD;
  const u16* kp = qkvb + QSZ + (size_t)bh * SEQ * HD;
  const u16* vp = qkvb + 2 * QSZ + (size_t)bh * SEQ * HD;
  __shared__ __align__(16) u16 vT[HD * 136];
  __shared__ __align__(16) u16 P[SEQ * 136];
  {
    const int s = tid & 127, half = tid >> 7;
    #pragma unroll
    for (int rr = 0; rr < 4; rr++) {
      const int e0 = half * 32 + rr * 8;
      short8 v8 = *(const short8*)&vp[s * HD + e0];
      #pragma unroll
      for (int j = 0; j < 8; j++) vT[(e0 + j) * 136 + s] = (u16)v8[j];
    }
  }
  const int fr = lane & 15, fg = lane >> 4;
  f32x4 sacc[2][8] = {};
  #pragma unroll
  for (int ks = 0; ks < 2; ks++) {
    const int k0 = ks * 32 + fg * 8;
    short8 qf[2], kf[8];
    #pragma unroll
    for (int mi = 0; mi < 2; mi++) qf[mi] = *(const short8*)&qp[(w*32 + mi*16 + fr) * HD + k0];
    #pragma unroll
    for (int ni = 0; ni < 8; ni++) kf[ni] = *(const short8*)&kp[(ni*16 + fr) * HD + k0];
    #pragma unroll
    for (int mi = 0; mi < 2; mi++)
      #pragma unroll
      for (int ni = 0; ni < 8; ni++)
        sacc[mi][ni] = __builtin_amdgcn_mfma_f32_16x16x32_bf16(qf[mi], kf[ni], sacc[mi][ni], 0, 0, 0);
  }
  const u16* bt = biasT + (size_t)bh * SEQ * SEQ;
  #pragma unroll
  for (int mi = 0; mi < 2; mi++) {
    #pragma unroll
    for (int j = 0; j < 4; j++) {
      const int l = w*32 + mi*16 + fg*4 + j;
      float vals[8];
      float mx = -1e30f;
      #pragma unroll
      for (int ni = 0; ni < 8; ni++) {
        vals[ni] = sacc[mi][ni][j] * 0.125f + bf2f(bt[l * SEQ + ni*16 + fr]);
        mx = fmaxf(mx, vals[ni]);
      }
      #pragma unroll
      for (int d = 1; d < 16; d <<= 1) mx = fmaxf(mx, __shfl_xor(mx, d));
      float sum = 0.f;
      #pragma unroll
      for (int ni = 0; ni < 8; ni++) { vals[ni] = __expf(vals[ni] - mx); sum += vals[ni]; }
      #pragma unroll
      for (int d = 1; d < 16; d <<= 1) sum += __shfl_xor(sum, d);
      const float inv = 1.0f / sum;
      #pragma unroll
      for (int ni = 0; ni < 8; ni++) P[l * 136 + ni*16 + fr] = f2bf(vals[ni] * inv);
    }
  }
  __syncthreads();
  f32x4 oacc[2][4] = {};
  #pragma unroll
  for (int ss = 0; ss < 4; ss++) {
    const int s0 = ss * 32 + fg * 8;
    short8 pf[2], vf[4];
    #pragma unroll
    for (int mi = 0; mi < 2; mi++) pf[mi] = *(const short8*)&P[(w*32 + mi*16 + fr) * 136 + s0];
    #pragma unroll
    for (int ei = 0; ei < 4; ei++) vf[ei] = *(const short8*)&vT[(ei*16 + fr) * 136 + s0];
    #pragma unroll
    for (int mi = 0; mi < 2; mi++)
      #pragma unroll
      for (int ei = 0; ei < 4; ei++)
        oacc[mi][ei] = __builtin_amdgcn_mfma_f32_16x16x32_bf16(pf[mi], vf[ei], oacc[mi][ei], 0, 0, 0);
  }
  #pragma unroll
  for (int mi = 0; mi < 2; mi++)
    #pragma unroll
    for (int ei = 0; ei < 4; ei++)
      #pragma unroll
      for (int j = 0; j < 4; j++) {
        const int r = b * SEQ + w*32 + mi*16 + fg*4 + j;
        const int c = h * HD + ei*16 + fr;
        ab[(size_t)r * DM + c] = f2bf(oacc[mi][ei][j]);
      }
}

// ---------------- BatchNorm finalize from fused partials ---------------------
template<bool FINAL>
__global__ __launch_bounds__(256)
void bn_final(const float* __restrict__ p1, const float* __restrict__ p2,
              const float* __restrict__ ga, const float* __restrict__ be,
              const float* __restrict__ gb, const float* __restrict__ beb,
              float* __restrict__ sc, float* __restrict__ sh)
{
  const int c = blockIdx.x * 256 + threadIdx.x;
  float s = 0, q = 0;
  for (int i = 0; i < 224; i++) { s += p1[i * DM + c]; q += p2[i * DM + c]; }
  const float mean = s * (1.0f / MTOK);
  const float var = q * (1.0f / MTOK) - mean * mean;
  const float rstd = rsqrtf(var + 1e-5f);
  if constexpr (!FINAL) {
    const float g = ga[c] * rstd;
    sc[c] = g;
    sh[c] = be[c] - mean * g;
  } else {
    const float sc2 = ga[c] * rstd;
    const float sh2 = be[c] - mean * sc2;
    const float varf = sc2 * sc2 * var;
    const float meanf = sc2 * mean + sh2;
    const float scf = gb[c] * rsqrtf(varf + 1e-5f);
    const float shf = beb[c] - meanf * scf;
    sc[c] = scf * sc2;
    sh[c] = scf * sh2 + shf;
  }
}

// MODE 0: write xb (bf16) only (intermediate); MODE 1: write out f32 (final)
template<int MODE>
__global__ __launch_bounds__(256)
void bn_apply(const float* __restrict__ xi, const float* __restrict__ sc,
              const float* __restrict__ sh, float* __restrict__ xo, u16* __restrict__ xb)
{
  const int i = blockIdx.x * 256 + threadIdx.x;
  const int cv = i % (DM / 4);
  float4 v = ((const float4*)xi)[i];
  const float4 s = ((const float4*)sc)[cv];
  const float4 h = ((const float4*)sh)[cv];
  float4 y;
  y.x = v.x * s.x + h.x; y.y = v.y * s.y + h.y;
  y.z = v.z * s.z + h.z; y.w = v.w * s.w + h.w;
  if constexpr (MODE == 1) {
    ((float4*)xo)[i] = y;
  } else {
    us4 pk; pk[0] = f2bf(y.x); pk[1] = f2bf(y.y); pk[2] = f2bf(y.z); pk[3] = f2bf(y.w);
    *(us4*)(xb + (size_t)i * 4) = pk;
  }
}

// ---------------- setup kernels ----------------------------------------------
__global__ __launch_bounds__(256)
void conv_bf16(const float* __restrict__ s, u16* __restrict__ d, int n4)
{
  const int i = blockIdx.x * 256 + threadIdx.x;
  if (i >= n4) return;
  float4 v = ((const float4*)s)[i];
  us4 pk; pk[0] = f2bf(v.x); pk[1] = f2bf(v.y); pk[2] = f2bf(v.z); pk[3] = f2bf(v.w);
  *(us4*)(d + (size_t)i * 4) = pk;
}

__global__ __launch_bounds__(256)
void conv_qkvw(const float* __restrict__ wq, const float* __restrict__ wk,
               const float* __restrict__ wv, u16* __restrict__ d)
{
  const int i = blockIdx.x * 256 + threadIdx.x;
  const int per = QKVN * DM / 4;
  const int l = i / per;
  const int rem = i - l * per;
  const int r = rem / (DM / 4);
  const int cv = rem - r * (DM / 4);
  const float* srcrow;
  if (r < DM)          srcrow = wq + ((size_t)l * DM + r) * DM;
  else if (r < 2 * DM) srcrow = wk + ((size_t)l * DM + (r - DM)) * DM;
  else                 srcrow = wv + ((size_t)l * DM + (r - 2 * DM)) * DM;
  float4 v = ((const float4*)srcrow)[cv];
  us4 pk; pk[0] = f2bf(v.x); pk[1] = f2bf(v.y); pk[2] = f2bf(v.z); pk[3] = f2bf(v.w);
  *(us4*)(d + (size_t)i * 4) = pk;
}

__global__ __launch_bounds__(256)
void conv_bias_qkv(const float* __restrict__ bq, const float* __restrict__ bk,
                   const float* __restrict__ bv, float* __restrict__ d)
{
  const int i = blockIdx.x * 256 + threadIdx.x;
  const int l = i / QKVN;
  const int r = i - l * QKVN;
  float v;
  if (r < DM)          v = bq[l * DM + r];
  else if (r < 2 * DM) v = bk[l * DM + r - DM];
  else                 v = bv[l * DM + r - 2 * DM];
  d[i] = v;
}

__global__ __launch_bounds__(256)
void bias_tr(const float* __restrict__ src, u16* __restrict__ dst)
{
  const int l = blockIdx.x, b = blockIdx.y;
  __shared__ float row[SEQ * NH];
  const float* s = src + ((size_t)b * SEQ + l) * SEQ * NH;
  for (int i = threadIdx.x; i < SEQ * NH; i += 256) row[i] = s[i];
  __syncthreads();
  for (int i = threadIdx.x; i < SEQ * NH; i += 256) {
    const int h = i >> 7, ss = i & 127;
    dst[((size_t)(b * NH + h) * SEQ + l) * SEQ + ss] = f2bf(row[ss * NH + h]);
  }
}

// ---------------- launch -----------------------------------------------------
extern "C" void kernel_launch(void* const* d_in, const int* in_sizes, int n_in,
                              void* d_out, int out_size, void* d_ws, size_t ws_size,
                              hipStream_t stream)
{
  const float* x    = (const float*)d_in[0];
  const float* abia = (const float*)d_in[1];
  const float* Wq   = (const float*)d_in[2];
  const float* bq   = (const float*)d_in[3];
  const float* Wk   = (const float*)d_in[4];
  const float* bk   = (const float*)d_in[5];
  const float* Wv   = (const float*)d_in[6];
  const float* bv   = (const float*)d_in[7];
  const float* Wo   = (const float*)d_in[8];
  const float* bo   = (const float*)d_in[9];
  const float* W1   = (const float*)d_in[10];
  const float* b1   = (const float*)d_in[11];
  const float* W2   = (const float*)d_in[12];
  const float* b2   = (const float*)d_in[13];
  const float* g1   = (const float*)d_in[14];
  const float* be1  = (const float*)d_in[15];
  const float* g2   = (const float*)d_in[16];
  const float* be2  = (const float*)d_in[17];
  const float* gf   = (const float*)d_in[18];
  const float* bef  = (const float*)d_in[19];
  float* out = (float*)d_out;

  char* ws = (char*)d_ws;
  size_t off = 0;
  auto alloc = [&](size_t n) -> char* {
    char* p = ws + off;
    off = (off + n + 255) & ~(size_t)255;
    return p;
  };
  u16*  wqkv  = (u16*)alloc((size_t)3 * QKVN * DM * 2);
  u16*  wo    = (u16*)alloc((size_t)3 * DM * DM * 2);
  u16*  w1    = (u16*)alloc((size_t)3 * FF * DM * 2);
  u16*  w2    = (u16*)alloc((size_t)3 * DM * FF * 2);
  float* bqkv = (float*)alloc((size_t)3 * QKVN * 4);
  u16*  xb    = (u16*)alloc((size_t)MTOK * DM * 2);
  u16*  ab    = (u16*)alloc((size_t)MTOK * DM * 2);
  u16*  big   = (u16*)alloc((size_t)MTOK * FF * 2);
  u16*  biasT = (u16*)alloc((size_t)HEADTOT * SEQ * SEQ * 2);
  float* p1   = (float*)alloc((size_t)224 * DM * 4);
  float* p2   = (float*)alloc((size_t)224 * DM * 4);
  float* sc   = (float*)alloc(DM * 4);
  float* sh   = (float*)alloc(DM * 4);
  if (off > ws_size) return;

  conv_qkvw<<<5184, 256, 0, stream>>>(Wq, Wk, Wv, wqkv);
  conv_bf16<<<1728, 256, 0, stream>>>(Wo, wo, 3 * DM * DM / 4);
  conv_bf16<<<6912, 256, 0, stream>>>(W1, w1, 3 * FF * DM / 4);
  conv_bf16<<<6912, 256, 0, stream>>>(W2, w2, 3 * DM * FF / 4);
  conv_bias_qkv<<<27, 256, 0, stream>>>(bq, bk, bv, bqkv);
  bias_tr<<<dim3(SEQ, NB), 256, 0, stream>>>(abia, biasT);
  conv_bf16<<<MTOK * DM / 4 / 256, 256, 0, stream>>>(x, xb, MTOK * DM / 4);

  auto gemm = [&](int epi, const u16* Ap, const u16* Wp, const float* bp,
                  u16* ob, float* o32, const u16* rs, int M, int N, int K) {
    const int Nt = N / 128;
    const int tiles = (M / 128) * Nt;          // 112 * Nt
    const int grid = 672;
    const int tpb = tiles / grid;              // QKV 3, FFN1 4, O/FFN2 1
    if (epi == 1)
      gemm_bt<1><<<grid, 256, 0, stream>>>(Ap, Wp, bp, ob, o32, rs, p1, p2, M, N, K, Nt, tpb);
    else if (epi == 2)
      gemm_bt<2><<<grid, 256, 0, stream>>>(Ap, Wp, bp, ob, o32, rs, p1, p2, M, N, K, Nt, tpb);
    else
      gemm_bt<3><<<grid, 256, 0, stream>>>(Ap, Wp, bp, ob, o32, rs, p1, p2, M, N, K, Nt, tpb);
  };

  for (int l = 0; l < NLAYER; l++) {
    gemm(3, xb, wqkv + (size_t)l * QKVN * DM, bqkv + l * QKVN, big, nullptr, nullptr,
         MTOK, QKVN, DM);
    attn_kernel<<<dim3(NH, NB), 256, 0, stream>>>(big, biasT, ab);
    gemm(2, ab, wo + (size_t)l * DM * DM, bo + l * DM, nullptr, out, xb,
         MTOK, DM, DM);
    bn_final<false><<<3, 256, 0, stream>>>(p1, p2, g1 + l * DM, be1 + l * DM,
                                           nullptr, nullptr, sc, sh);
    bn_apply<0><<<MTOK * DM / 4 / 256, 256, 0, stream>>>(out, sc, sh, nullptr, xb);
    gemm(1, xb, w1 + (size_t)l * FF * DM, b1 + l * FF, big, nullptr, nullptr,
         MTOK, FF, DM);
    gemm(2, big, w2 + (size_t)l * DM * FF, b2 + l * DM, nullptr, out, xb,
         MTOK, DM, FF);
    if (l < NLAYER - 1) {
      bn_final<false><<<3, 256, 0, stream>>>(p1, p2, g2 + l * DM, be2 + l * DM,
                                             nullptr, nullptr, sc, sh);
      bn_apply<0><<<MTOK * DM / 4 / 256, 256, 0, stream>>>(out, sc, sh, nullptr, xb);
    } else {
      bn_final<true><<<3, 256, 0, stream>>>(p1, p2, g2 + l * DM, be2 + l * DM,
                                            gf, bef, sc, sh);
      bn_apply<1><<<MTOK * DM / 4 / 256, 256, 0, stream>>>(out, sc, sh, out, nullptr);
    }
  }
}

// Round 14
// 1145.625 us; speedup vs baseline: 1.1478x; 1.1478x over previous
//
#include <hip/hip_runtime.h>

#define NB 112
#define SEQ 128
#define DM 768
#define NH 12
#define HD 64
#define FF 3072
#define NLAYER 3
#define MTOK (NB*SEQ)            // 14336
#define QKVN (3*DM)              // 2304
#define HEADTOT (NB*NH)          // 1344
#define QSZ ((size_t)HEADTOT*SEQ*HD)   // 11010048 elems per q/k/v

typedef unsigned short u16;
typedef __attribute__((ext_vector_type(8))) short short8;
typedef __attribute__((ext_vector_type(4))) float f32x4;
typedef __attribute__((ext_vector_type(4))) unsigned short us4;

__device__ __forceinline__ u16 f2bf(float f){
  unsigned u = __builtin_bit_cast(unsigned, f);
  u += 0x7FFFu + ((u >> 16) & 1u);
  return (u16)(u >> 16);
}
__device__ __forceinline__ float bf2f(u16 b){
  unsigned u = ((unsigned)b) << 16;
  return __builtin_bit_cast(float, u);
}
// packed RNE f32x2 -> bf16x2 (lo=s0, hi=s1)
__device__ __forceinline__ unsigned cvt_pk_bf16(float lo, float hi){
  unsigned r;
  asm("v_cvt_pk_bf16_f32 %0, %1, %2" : "=v"(r) : "v"(lo), "v"(hi));
  return r;
}
// tanh-GELU in sigmoid form: 0.5x(1+tanh(z)) == x / (1 + e^{-2z})
__device__ __forceinline__ float gelu_t(float x){
  const float t = -1.5957691216057308f * x * __builtin_fmaf(0.044715f, x*x, 1.0f);
  return __fdividef(x, 1.0f + __expf(t));
}

__device__ __forceinline__ void gl_lds16(const void* g, void* l){
  __builtin_amdgcn_global_load_lds((const __attribute__((address_space(1))) unsigned*)g,
                                   (__attribute__((address_space(3))) unsigned*)l, 16, 0, 0);
}

// ================= persistent 256x256 GEMM, 2 merged phases/K-tile ==========
// (r11 structure, verified best: 1151 us, MfmaUtil 25.5, conflicts 0)
// C[m,n] = sum_k A[m,k]*W[n,k]. 512 thr = 8 waves (2M x 4N).
// PA = mh0 x {k0,k1} (32 MFMA), PB = mh1 x {k0,k1}. 4 barriers/iter.
//   PA stages B0(t+1), B1(t+1);   after MFMA: vmcnt(4)
//   PB stages A0(t+2), A1(t+1);   after MFMA: vmcnt(4)/(2)
// EPI: 1 = gelu(acc+bias)->bf16 ; 2 = y=acc+bias+res(bf16) -> f32 + BN partials ;
//      3 = qkv head-scatter bf16
template<int EPI>
__global__ __launch_bounds__(512, 2)
void gemm_bt(const u16* __restrict__ A, const u16* __restrict__ W,
             const float* __restrict__ bias, u16* __restrict__ obf,
             float* __restrict__ of32, const u16* __restrict__ res,
             float* __restrict__ p1, float* __restrict__ p2,
             int M, int N, int K, int Nt, int TPB)
{
  __shared__ __align__(16) char smem[131072];
  const int tid = threadIdx.x;
  const int w = tid >> 6, lane = tid & 63;
  const int wm = w >> 2, wn = w & 3;
  const int fr = lane & 15, fg = lane >> 4;
  const int fko = fg * 8;
  const int grid = gridDim.x;
  const int q8 = grid >> 3, r8 = grid & 7;
  const int xcd = blockIdx.x & 7, pos = blockIdx.x >> 3;
  const int start = xcd < r8 ? xcd * (q8 + 1) : r8 * (q8 + 1) + (xcd - r8) * q8;
  const int swz = start + pos;
  const int nt = K >> 6;
  const int tot = TPB * nt;
  const int l3 = lane >> 3;
  const int k16s = ((lane & 7) ^ l3) * 8;
  int rowAK[2][2], rowBK[2][2];
  #pragma unroll
  for (int mh = 0; mh < 2; mh++)
    #pragma unroll
    for (int j = 0; j < 2; j++)
      rowAK[mh][j] = (mh*64 + j*128 + w*8 + l3) * K;
  #pragma unroll
  for (int h = 0; h < 2; h++)
    #pragma unroll
    for (int j = 0; j < 2; j++)
      rowBK[h][j] = (h*128 + (w + j*8)*8 + l3) * K;

  auto stA2 = [&](int bb, int mh, int soff) {
    const u16* g0 = A + (size_t)soff + rowAK[mh][0] + k16s;
    const u16* g1 = A + (size_t)soff + rowAK[mh][1] + k16s;
    char* d = smem + bb*65536 + (mh*64 + w*8)*128;
    gl_lds16(g0, d);
    gl_lds16(g1, d + 16384);
  };
  auto stB2 = [&](int bb, int h, int soff) {
    const u16* g0 = W + (size_t)soff + rowBK[h][0] + k16s;
    const u16* g1 = W + (size_t)soff + rowBK[h][1] + k16s;
    char* d = smem + bb*65536 + 32768 + (h*128 + w*8)*128;
    gl_lds16(g0, d);
    gl_lds16(g1, d + 8192);
  };
  const int axor = (fr & 7) << 4;
  auto rdA2 = [&](int bb, int mh, int kh, int mf) -> short8 {
    const int row = wm*128 + mh*64 + mf*16 + fr;
    return *(const short8*)(smem + bb*65536 + row*128 + (((kh*32 + fko)*2) ^ axor));
  };
  auto rdB2 = [&](int bb, int kh, int nf) -> short8 {
    const int row = wn*64 + nf*16 + fr;
    return *(const short8*)(smem + bb*65536 + 32768 + row*128 + (((kh*32 + fko)*2) ^ axor));
  };
  auto coord = [&](int r, int& bm, int& bn) {
    const int lin = swz * TPB + r;
    const int mI = lin / Nt;
    bm = mI * 256; bn = (lin - mI * Nt) * 256;
  };

  f32x4 acc[8][4] = {};

  auto epi = [&](int bm, int bn) {
    float bs[4] = {0,0,0,0}, bq[4] = {0,0,0,0};
    #pragma unroll
    for (int mi = 0; mi < 8; mi++) {
      #pragma unroll
      for (int ni = 0; ni < 4; ni++) {
        const int c = bn + wn*64 + ni*16 + fr;
        const int r0 = bm + wm*128 + (mi>>2)*64 + (mi&3)*16 + fg*4;
        const float bc = bias[c];
        float v[4];
        #pragma unroll
        for (int j = 0; j < 4; j++) v[j] = acc[mi][ni][j] + bc;
        if constexpr (EPI == 1) {
          #pragma unroll
          for (int j = 0; j < 4; j++) v[j] = gelu_t(v[j]);
          const unsigned p01 = cvt_pk_bf16(v[0], v[1]);
          const unsigned p23 = cvt_pk_bf16(v[2], v[3]);
          u16* d = obf + (size_t)r0 * N + c;
          d[0] = (u16)p01; d[N] = (u16)(p01 >> 16);
          d[2*N] = (u16)p23; d[3*N] = (u16)(p23 >> 16);
        } else if constexpr (EPI == 2) {
          #pragma unroll
          for (int j = 0; j < 4; j++) {
            const float y = v[j] + bf2f(res[(size_t)(r0+j) * N + c]);
            of32[(size_t)(r0+j) * N + c] = y;
            bs[ni] += y; bq[ni] += y * y;
          }
        } else {
          const int which = c / DM;
          const int cc = c - which * DM;
          const int hh = cc >> 6, e = cc & 63;
          const int bb = r0 >> 7, l = r0 & 127;
          const unsigned p01 = cvt_pk_bf16(v[0], v[1]);
          const unsigned p23 = cvt_pk_bf16(v[2], v[3]);
          u16* d = obf + (size_t)which * QSZ + ((size_t)(bb*NH + hh) * SEQ + l) * HD + e;
          d[0] = (u16)p01; d[HD] = (u16)(p01 >> 16);
          d[2*HD] = (u16)p23; d[3*HD] = (u16)(p23 >> 16);
        }
        acc[mi][ni] = (f32x4){0.f, 0.f, 0.f, 0.f};
      }
    }
    if constexpr (EPI == 2) {
      const int mIdx = bm >> 8;
      #pragma unroll
      for (int ni = 0; ni < 4; ni++) {
        float s = bs[ni], qq = bq[ni];
        s  += __shfl_xor(s, 16);  s  += __shfl_xor(s, 32);
        qq += __shfl_xor(qq, 16); qq += __shfl_xor(qq, 32);
        if (fg == 0) {
          const int c = bn + wn*64 + ni*16 + fr;
          p1[(mIdx*2 + wm) * N + c] = s;
          p2[(mIdx*2 + wm) * N + c] = qq;
        }
      }
    }
  };

  int r0t = 0, kt0 = 0, bm0, bn0; coord(0, bm0, bn0);
  int r1 = 0, kt1 = 1, bm1 = bm0, bn1 = bn0;
  int r2 = 0, kt2 = 2, bm2 = bm0;
  if (kt2 >= nt) { kt2 -= nt; r2 = 1; int d; if (r2 < TPB) coord(r2, bm2, d); }

  stA2(0, 0, bm0*K); stA2(0, 1, bm0*K);
  stB2(0, 0, bn0*K); stB2(0, 1, bn0*K);
  if (tot > 1) stA2(1, 0, bm1*K + kt1*64);
  asm volatile("s_waitcnt vmcnt(2)" ::: "memory");
  __builtin_amdgcn_s_barrier();

  short8 a0[4], a1[4], bk0[4], bk1[4];
  for (int it = 0; it < tot; ++it) {
    const int bufc = it & 1, nb = bufc ^ 1;
    const bool st1 = (it + 1 < tot), st2 = (it + 2 < tot);
    const int sB1 = bn1*K + kt1*64;
    const int sA1 = bm1*K + kt1*64;
    const int sA2 = bm2*K + kt2*64;
    // ---------------- PA: mh0 x {k0,k1}  (32 MFMA) ----------------
    #pragma unroll
    for (int i = 0; i < 4; i++) a0[i] = rdA2(bufc, 0, 0, i);
    #pragma unroll
    for (int i = 0; i < 4; i++) a1[i] = rdA2(bufc, 0, 1, i);
    #pragma unroll
    for (int i = 0; i < 4; i++) bk0[i] = rdB2(bufc, 0, i);
    #pragma unroll
    for (int i = 0; i < 4; i++) bk1[i] = rdB2(bufc, 1, i);
    if (st1) { stB2(nb, 0, sB1); stB2(nb, 1, sB1); }
    __builtin_amdgcn_s_barrier();
    asm volatile("s_waitcnt lgkmcnt(0)" ::: "memory");
    __builtin_amdgcn_sched_barrier(0);
    __builtin_amdgcn_s_setprio(1);
    #pragma unroll
    for (int mi = 0; mi < 4; mi++)
      #pragma unroll
      for (int ni = 0; ni < 4; ni++)
        acc[mi][ni] = __builtin_amdgcn_mfma_f32_16x16x32_bf16(a0[mi], bk0[ni], acc[mi][ni], 0, 0, 0);
    #pragma unroll
    for (int mi = 0; mi < 4; mi++)
      #pragma unroll
      for (int ni = 0; ni < 4; ni++)
        acc[mi][ni] = __builtin_amdgcn_mfma_f32_16x16x32_bf16(a1[mi], bk1[ni], acc[mi][ni], 0, 0, 0);
    __builtin_amdgcn_s_setprio(0);
    if (st1) { asm volatile("s_waitcnt vmcnt(4)" ::: "memory"); }
    else     { asm volatile("s_waitcnt vmcnt(0)" ::: "memory"); }
    __builtin_amdgcn_s_barrier();
    // ---------------- PB: mh1 x {k0,k1}  (32 MFMA) ----------------
    #pragma unroll
    for (int i = 0; i < 4; i++) a0[i] = rdA2(bufc, 1, 0, i);
    #pragma unroll
    for (int i = 0; i < 4; i++) a1[i] = rdA2(bufc, 1, 1, i);
    if (st2) stA2(bufc, 0, sA2);
    if (st1) stA2(nb, 1, sA1);
    __builtin_amdgcn_s_barrier();
    asm volatile("s_waitcnt lgkmcnt(0)" ::: "memory");
    __builtin_amdgcn_sched_barrier(0);
    __builtin_amdgcn_s_setprio(1);
    #pragma unroll
    for (int mi = 0; mi < 4; mi++)
      #pragma unroll
      for (int ni = 0; ni < 4; ni++)
        acc[4+mi][ni] = __builtin_amdgcn_mfma_f32_16x16x32_bf16(a0[mi], bk0[ni], acc[4+mi][ni], 0, 0, 0);
    #pragma unroll
    for (int mi = 0; mi < 4; mi++)
      #pragma unroll
      for (int ni = 0; ni < 4; ni++)
        acc[4+mi][ni] = __builtin_amdgcn_mfma_f32_16x16x32_bf16(a1[mi], bk1[ni], acc[4+mi][ni], 0, 0, 0);
    __builtin_amdgcn_s_setprio(0);
    if (st2)      { asm volatile("s_waitcnt vmcnt(4)" ::: "memory"); }
    else if (st1) { asm volatile("s_waitcnt vmcnt(2)" ::: "memory"); }
    __builtin_amdgcn_s_barrier();
    if (kt0 == nt - 1) {
      epi(bm0, bn0);
      kt0 = 0; r0t++;
      if (r0t < TPB) coord(r0t, bm0, bn0);
    } else kt0++;
    kt1++; if (kt1 == nt) { kt1 = 0; r1++; if (r1 < TPB) coord(r1, bm1, bn1); }
    kt2++; if (kt2 == nt) { kt2 = 0; r2++; if (r2 < TPB) { int d; coord(r2, bm2, d); } }
  }
}

// ---------------- Attention: one block per (b,h) -----------------------------
__global__ __launch_bounds__(256)
void attn_kernel(const u16* __restrict__ qkvb, const u16* __restrict__ biasT,
                 u16* __restrict__ ab)
{
  const int h = blockIdx.x, b = blockIdx.y;
  const int tid = threadIdx.x, w = tid >> 6, lane = tid & 63;
  const int bh = b * NH + h;
  const u16* qp = qkvb + (size_t)bh * SEQ * HD;
  const u16* kp = qkvb + QSZ + (size_t)bh * SEQ * HD;
  const u16* vp = qkvb + 2 * QSZ + (size_t)bh * SEQ * HD;
  __shared__ __align__(16) u16 vT[HD * 136];
  __shared__ __align__(16) u16 P[SEQ * 136];
  {
    const int s = tid & 127, half = tid >> 7;
    #pragma unroll
    for (int rr = 0; rr < 4; rr++) {
      const int e0 = half * 32 + rr * 8;
      short8 v8 = *(const short8*)&vp[s * HD + e0];
      #pragma unroll
      for (int j = 0; j < 8; j++) vT[(e0 + j) * 136 + s] = (u16)v8[j];
    }
  }
  const int fr = lane & 15, fg = lane >> 4;
  f32x4 sacc[2][8] = {};
  #pragma unroll
  for (int ks = 0; ks < 2; ks++) {
    const int k0 = ks * 32 + fg * 8;
    short8 qf[2], kf[8];
    #pragma unroll
    for (int mi = 0; mi < 2; mi++) qf[mi] = *(const short8*)&qp[(w*32 + mi*16 + fr) * HD + k0];
    #pragma unroll
    for (int ni = 0; ni < 8; ni++) kf[ni] = *(const short8*)&kp[(ni*16 + fr) * HD + k0];
    #pragma unroll
    for (int mi = 0; mi < 2; mi++)
      #pragma unroll
      for (int ni = 0; ni < 8; ni++)
        sacc[mi][ni] = __builtin_amdgcn_mfma_f32_16x16x32_bf16(qf[mi], kf[ni], sacc[mi][ni], 0, 0, 0);
  }
  const u16* bt = biasT + (size_t)bh * SEQ * SEQ;
  #pragma unroll
  for (int mi = 0; mi < 2; mi++) {
    #pragma unroll
    for (int j = 0; j < 4; j++) {
      const int l = w*32 + mi*16 + fg*4 + j;
      float vals[8];
      float mx = -1e30f;
      #pragma unroll
      for (int ni = 0; ni < 8; ni++) {
        vals[ni] = sacc[mi][ni][j] * 0.125f + bf2f(bt[l * SEQ + ni*16 + fr]);
        mx = fmaxf(mx, vals[ni]);
      }
      #pragma unroll
      for (int d = 1; d < 16; d <<= 1) mx = fmaxf(mx, __shfl_xor(mx, d));
      float sum = 0.f;
      #pragma unroll
      for (int ni = 0; ni < 8; ni++) { vals[ni] = __expf(vals[ni] - mx); sum += vals[ni]; }
      #pragma unroll
      for (int d = 1; d < 16; d <<= 1) sum += __shfl_xor(sum, d);
      const float inv = 1.0f / sum;
      #pragma unroll
      for (int ni = 0; ni < 8; ni++) P[l * 136 + ni*16 + fr] = f2bf(vals[ni] * inv);
    }
  }
  __syncthreads();
  f32x4 oacc[2][4] = {};
  #pragma unroll
  for (int ss = 0; ss < 4; ss++) {
    const int s0 = ss * 32 + fg * 8;
    short8 pf[2], vf[4];
    #pragma unroll
    for (int mi = 0; mi < 2; mi++) pf[mi] = *(const short8*)&P[(w*32 + mi*16 + fr) * 136 + s0];
    #pragma unroll
    for (int ei = 0; ei < 4; ei++) vf[ei] = *(const short8*)&vT[(ei*16 + fr) * 136 + s0];
    #pragma unroll
    for (int mi = 0; mi < 2; mi++)
      #pragma unroll
      for (int ei = 0; ei < 4; ei++)
        oacc[mi][ei] = __builtin_amdgcn_mfma_f32_16x16x32_bf16(pf[mi], vf[ei], oacc[mi][ei], 0, 0, 0);
  }
  #pragma unroll
  for (int mi = 0; mi < 2; mi++)
    #pragma unroll
    for (int ei = 0; ei < 4; ei++)
      #pragma unroll
      for (int j = 0; j < 4; j++) {
        const int r = b * SEQ + w*32 + mi*16 + fg*4 + j;
        const int c = h * HD + ei*16 + fr;
        ab[(size_t)r * DM + c] = f2bf(oacc[mi][ei][j]);
      }
}

// ---------------- BatchNorm finalize from fused partials ---------------------
template<bool FINAL>
__global__ __launch_bounds__(256)
void bn_final(const float* __restrict__ p1, const float* __restrict__ p2,
              const float* __restrict__ ga, const float* __restrict__ be,
              const float* __restrict__ gb, const float* __restrict__ beb,
              float* __restrict__ sc, float* __restrict__ sh)
{
  const int c = blockIdx.x * 256 + threadIdx.x;
  float s = 0, q = 0;
  for (int i = 0; i < 112; i++) { s += p1[i * DM + c]; q += p2[i * DM + c]; }
  const float mean = s * (1.0f / MTOK);
  const float var = q * (1.0f / MTOK) - mean * mean;
  const float rstd = rsqrtf(var + 1e-5f);
  if constexpr (!FINAL) {
    const float g = ga[c] * rstd;
    sc[c] = g;
    sh[c] = be[c] - mean * g;
  } else {
    const float sc2 = ga[c] * rstd;
    const float sh2 = be[c] - mean * sc2;
    const float varf = sc2 * sc2 * var;
    const float meanf = sc2 * mean + sh2;
    const float scf = gb[c] * rsqrtf(varf + 1e-5f);
    const float shf = beb[c] - meanf * scf;
    sc[c] = scf * sc2;
    sh[c] = scf * sh2 + shf;
  }
}

// MODE 0: write xb (bf16) only (intermediate); MODE 1: write out f32 (final)
// 8 floats per thread (G13 vectorization)
template<int MODE>
__global__ __launch_bounds__(256)
void bn_apply(const float* __restrict__ xi, const float* __restrict__ sc,
              const float* __restrict__ sh, float* __restrict__ xo, u16* __restrict__ xb)
{
  const int i = blockIdx.x * 256 + threadIdx.x;   // 8-float units, total MTOK*DM/8
  const int c0 = (i % (DM / 8)) * 2;              // in float4 units
  float4 v0 = ((const float4*)xi)[i*2];
  float4 v1 = ((const float4*)xi)[i*2 + 1];
  const float4 s0 = ((const float4*)sc)[c0];
  const float4 s1 = ((const float4*)sc)[c0 + 1];
  const float4 h0 = ((const float4*)sh)[c0];
  const float4 h1 = ((const float4*)sh)[c0 + 1];
  float y0x = __builtin_fmaf(v0.x, s0.x, h0.x), y0y = __builtin_fmaf(v0.y, s0.y, h0.y);
  float y0z = __builtin_fmaf(v0.z, s0.z, h0.z), y0w = __builtin_fmaf(v0.w, s0.w, h0.w);
  float y1x = __builtin_fmaf(v1.x, s1.x, h1.x), y1y = __builtin_fmaf(v1.y, s1.y, h1.y);
  float y1z = __builtin_fmaf(v1.z, s1.z, h1.z), y1w = __builtin_fmaf(v1.w, s1.w, h1.w);
  if constexpr (MODE == 1) {
    ((float4*)xo)[i*2]     = (float4){y0x, y0y, y0z, y0w};
    ((float4*)xo)[i*2 + 1] = (float4){y1x, y1y, y1z, y1w};
  } else {
    short8 r;
    unsigned pA = cvt_pk_bf16(y0x, y0y), pB = cvt_pk_bf16(y0z, y0w);
    unsigned pC = cvt_pk_bf16(y1x, y1y), pD = cvt_pk_bf16(y1z, y1w);
    r[0] = (short)(u16)pA; r[1] = (short)(u16)(pA >> 16);
    r[2] = (short)(u16)pB; r[3] = (short)(u16)(pB >> 16);
    r[4] = (short)(u16)pC; r[5] = (short)(u16)(pC >> 16);
    r[6] = (short)(u16)pD; r[7] = (short)(u16)(pD >> 16);
    *(short8*)&xb[(size_t)i * 8] = r;
  }
}

// ---------------- setup kernels ----------------------------------------------
// 8 floats per thread
__global__ __launch_bounds__(256)
void conv_bf16(const float* __restrict__ s, u16* __restrict__ d, int n8)
{
  const int i = blockIdx.x * 256 + threadIdx.x;
  if (i >= n8) return;
  float4 v0 = ((const float4*)s)[i*2];
  float4 v1 = ((const float4*)s)[i*2 + 1];
  short8 r;
  unsigned pA = cvt_pk_bf16(v0.x, v0.y), pB = cvt_pk_bf16(v0.z, v0.w);
  unsigned pC = cvt_pk_bf16(v1.x, v1.y), pD = cvt_pk_bf16(v1.z, v1.w);
  r[0] = (short)(u16)pA; r[1] = (short)(u16)(pA >> 16);
  r[2] = (short)(u16)pB; r[3] = (short)(u16)(pB >> 16);
  r[4] = (short)(u16)pC; r[5] = (short)(u16)(pC >> 16);
  r[6] = (short)(u16)pD; r[7] = (short)(u16)(pD >> 16);
  *(short8*)&d[(size_t)i * 8] = r;
}

__global__ __launch_bounds__(256)
void conv_qkvw(const float* __restrict__ wq, const float* __restrict__ wk,
               const float* __restrict__ wv, u16* __restrict__ d)
{
  const int i = blockIdx.x * 256 + threadIdx.x;   // 8-float units
  const int per = QKVN * DM / 8;
  const int l = i / per;
  const int rem = i - l * per;
  const int r = rem / (DM / 8);
  const int cv = rem - r * (DM / 8);
  const float* srcrow;
  if (r < DM)          srcrow = wq + ((size_t)l * DM + r) * DM;
  else if (r < 2 * DM) srcrow = wk + ((size_t)l * DM + (r - DM)) * DM;
  else                 srcrow = wv + ((size_t)l * DM + (r - 2 * DM)) * DM;
  float4 v0 = ((const float4*)srcrow)[cv*2];
  float4 v1 = ((const float4*)srcrow)[cv*2 + 1];
  short8 o;
  unsigned pA = cvt_pk_bf16(v0.x, v0.y), pB = cvt_pk_bf16(v0.z, v0.w);
  unsigned pC = cvt_pk_bf16(v1.x, v1.y), pD = cvt_pk_bf16(v1.z, v1.w);
  o[0] = (short)(u16)pA; o[1] = (short)(u16)(pA >> 16);
  o[2] = (short)(u16)pB; o[3] = (short)(u16)(pB >> 16);
  o[4] = (short)(u16)pC; o[5] = (short)(u16)(pC >> 16);
  o[6] = (short)(u16)pD; o[7] = (short)(u16)(pD >> 16);
  *(short8*)&d[(size_t)i * 8] = o;
}

__global__ __launch_bounds__(256)
void conv_bias_qkv(const float* __restrict__ bq, const float* __restrict__ bk,
                   const float* __restrict__ bv, float* __restrict__ d)
{
  const int i = blockIdx.x * 256 + threadIdx.x;
  const int l = i / QKVN;
  const int r = i - l * QKVN;
  float v;
  if (r < DM)          v = bq[l * DM + r];
  else if (r < 2 * DM) v = bk[l * DM + r - DM];
  else                 v = bv[l * DM + r - 2 * DM];
  d[i] = v;
}

__global__ __launch_bounds__(256)
void bias_tr(const float* __restrict__ src, u16* __restrict__ dst)
{
  const int l = blockIdx.x, b = blockIdx.y;
  __shared__ float row[SEQ * NH];
  const float* s = src + ((size_t)b * SEQ + l) * SEQ * NH;
  for (int i = threadIdx.x; i < SEQ * NH; i += 256) row[i] = s[i];
  __syncthreads();
  for (int i = threadIdx.x; i < SEQ * NH; i += 256) {
    const int h = i >> 7, ss = i & 127;
    dst[((size_t)(b * NH + h) * SEQ + l) * SEQ + ss] = f2bf(row[ss * NH + h]);
  }
}

// ---------------- launch -----------------------------------------------------
extern "C" void kernel_launch(void* const* d_in, const int* in_sizes, int n_in,
                              void* d_out, int out_size, void* d_ws, size_t ws_size,
                              hipStream_t stream)
{
  const float* x    = (const float*)d_in[0];
  const float* abia = (const float*)d_in[1];
  const float* Wq   = (const float*)d_in[2];
  const float* bq   = (const float*)d_in[3];
  const float* Wk   = (const float*)d_in[4];
  const float* bk   = (const float*)d_in[5];
  const float* Wv   = (const float*)d_in[6];
  const float* bv   = (const float*)d_in[7];
  const float* Wo   = (const float*)d_in[8];
  const float* bo   = (const float*)d_in[9];
  const float* W1   = (const float*)d_in[10];
  const float* b1   = (const float*)d_in[11];
  const float* W2   = (const float*)d_in[12];
  const float* b2   = (const float*)d_in[13];
  const float* g1   = (const float*)d_in[14];
  const float* be1  = (const float*)d_in[15];
  const float* g2   = (const float*)d_in[16];
  const float* be2  = (const float*)d_in[17];
  const float* gf   = (const float*)d_in[18];
  const float* bef  = (const float*)d_in[19];
  float* out = (float*)d_out;

  char* ws = (char*)d_ws;
  size_t off = 0;
  auto alloc = [&](size_t n) -> char* {
    char* p = ws + off;
    off = (off + n + 255) & ~(size_t)255;
    return p;
  };
  u16*  wqkv  = (u16*)alloc((size_t)3 * QKVN * DM * 2);
  u16*  wo    = (u16*)alloc((size_t)3 * DM * DM * 2);
  u16*  w1    = (u16*)alloc((size_t)3 * FF * DM * 2);
  u16*  w2    = (u16*)alloc((size_t)3 * DM * FF * 2);
  float* bqkv = (float*)alloc((size_t)3 * QKVN * 4);
  u16*  xb    = (u16*)alloc((size_t)MTOK * DM * 2);
  u16*  ab    = (u16*)alloc((size_t)MTOK * DM * 2);
  u16*  big   = (u16*)alloc((size_t)MTOK * FF * 2);
  u16*  biasT = (u16*)alloc((size_t)HEADTOT * SEQ * SEQ * 2);
  float* p1   = (float*)alloc((size_t)112 * DM * 4);
  float* p2   = (float*)alloc((size_t)112 * DM * 4);
  float* sc   = (float*)alloc(DM * 4);
  float* sh   = (float*)alloc(DM * 4);
  if (off > ws_size) return;

  conv_qkvw<<<2592, 256, 0, stream>>>(Wq, Wk, Wv, wqkv);
  conv_bf16<<<864, 256, 0, stream>>>(Wo, wo, 3 * DM * DM / 8);
  conv_bf16<<<3456, 256, 0, stream>>>(W1, w1, 3 * FF * DM / 8);
  conv_bf16<<<3456, 256, 0, stream>>>(W2, w2, 3 * DM * FF / 8);
  conv_bias_qkv<<<27, 256, 0, stream>>>(bq, bk, bv, bqkv);
  bias_tr<<<dim3(SEQ, NB), 256, 0, stream>>>(abia, biasT);
  conv_bf16<<<MTOK * DM / 8 / 256, 256, 0, stream>>>(x, xb, MTOK * DM / 8);

  auto gemm = [&](int epi, const u16* Ap, const u16* Wp, const float* bp,
                  u16* ob, float* o32, const u16* rs, int M, int N, int K) {
    const int Nt = N / 256;
    const int tiles = (M / 256) * Nt;
    const int tpb = (tiles + 255) / 256;
    const int grid = tiles / tpb;          // exact for all our shapes
    if (epi == 1)
      gemm_bt<1><<<grid, 512, 0, stream>>>(Ap, Wp, bp, ob, o32, rs, p1, p2, M, N, K, Nt, tpb);
    else if (epi == 2)
      gemm_bt<2><<<grid, 512, 0, stream>>>(Ap, Wp, bp, ob, o32, rs, p1, p2, M, N, K, Nt, tpb);
    else
      gemm_bt<3><<<grid, 512, 0, stream>>>(Ap, Wp, bp, ob, o32, rs, p1, p2, M, N, K, Nt, tpb);
  };

  for (int l = 0; l < NLAYER; l++) {
    gemm(3, xb, wqkv + (size_t)l * QKVN * DM, bqkv + l * QKVN, big, nullptr, nullptr,
         MTOK, QKVN, DM);
    attn_kernel<<<dim3(NH, NB), 256, 0, stream>>>(big, biasT, ab);
    gemm(2, ab, wo + (size_t)l * DM * DM, bo + l * DM, nullptr, out, xb,
         MTOK, DM, DM);
    bn_final<false><<<3, 256, 0, stream>>>(p1, p2, g1 + l * DM, be1 + l * DM,
                                           nullptr, nullptr, sc, sh);
    bn_apply<0><<<MTOK * DM / 8 / 256, 256, 0, stream>>>(out, sc, sh, nullptr, xb);
    gemm(1, xb, w1 + (size_t)l * FF * DM, b1 + l * FF, big, nullptr, nullptr,
         MTOK, FF, DM);
    gemm(2, big, w2 + (size_t)l * DM * FF, b2 + l * DM, nullptr, out, xb,
         MTOK, DM, FF);
    if (l < NLAYER - 1) {
      bn_final<false><<<3, 256, 0, stream>>>(p1, p2, g2 + l * DM, be2 + l * DM,
                                             nullptr, nullptr, sc, sh);
      bn_apply<0><<<MTOK * DM / 8 / 256, 256, 0, stream>>>(out, sc, sh, nullptr, xb);
    } else {
      bn_final<true><<<3, 256, 0, stream>>>(p1, p2, g2 + l * DM, be2 + l * DM,
                                            gf, bef, sc, sh);
      bn_apply<1><<<MTOK * DM / 8 / 256, 256, 0, stream>>>(out, sc, sh, out, nullptr);
    }
  }
}

// Round 15
// 1131.277 us; speedup vs baseline: 1.1624x; 1.0127x over previous
//
#include <hip/hip_runtime.h>

#define NB 112
#define SEQ 128
#define DM 768
#define NH 12
#define HD 64
#define FF 3072
#define NLAYER 3
#define MTOK (NB*SEQ)            // 14336
#define QKVN (3*DM)              // 2304
#define HEADTOT (NB*NH)          // 1344
#define QSZ ((size_t)HEADTOT*SEQ*HD)   // 11010048 elems per q/k/v

typedef unsigned short u16;
typedef __attribute__((ext_vector_type(8))) short short8;
typedef __attribute__((ext_vector_type(4))) float f32x4;
typedef __attribute__((ext_vector_type(4))) unsigned short us4;

__device__ __forceinline__ u16 f2bf(float f){
  unsigned u = __builtin_bit_cast(unsigned, f);
  u += 0x7FFFu + ((u >> 16) & 1u);
  return (u16)(u >> 16);
}
__device__ __forceinline__ float bf2f(u16 b){
  unsigned u = ((unsigned)b) << 16;
  return __builtin_bit_cast(float, u);
}
// packed RNE f32x2 -> bf16x2 (lo=s0, hi=s1)
__device__ __forceinline__ unsigned cvt_pk_bf16(float lo, float hi){
  unsigned r;
  asm("v_cvt_pk_bf16_f32 %0, %1, %2" : "=v"(r) : "v"(lo), "v"(hi));
  return r;
}
// tanh-GELU in sigmoid form: 0.5x(1+tanh(z)) == x / (1 + e^{-2z})
__device__ __forceinline__ float gelu_t(float x){
  const float t = -1.5957691216057308f * x * __builtin_fmaf(0.044715f, x*x, 1.0f);
  return __fdividef(x, 1.0f + __expf(t));
}

__device__ __forceinline__ void gl_lds16(const void* g, void* l){
  __builtin_amdgcn_global_load_lds((const __attribute__((address_space(1))) unsigned*)g,
                                   (__attribute__((address_space(3))) unsigned*)l, 16, 0, 0);
}

// ====== persistent 256x256 GEMM, A triple-buffered, 1 barrier/K-tile ========
// C[m,n] = sum_k A[m,k]*W[n,k]. 512 thr = 8 waves (2M x 4N).
// LDS 160KB: A slots 3 x 32KB (offset 0), B slots 2 x 32KB (offset 96KB).
// A(t+2) -> slot (t+2)%3 never collides with reads of slot t%3 / (t+1)%3,
// so the mid-iter barrier of the r11/r14 structure is GONE: one barrier +
// one counted vmcnt per K-tile. FIFO vmcnt accounting (issue B(t+1) BEFORE
// A(t+2)): queue at end-wait = {A(t+1), B(t+1), A(t+2)} -> vmcnt(4) drains
// A(t+1)+B(t+1), leaves A(t+2) in flight. Prologue vmcnt(4); tail vmcnt(0).
// EPI: 1 = gelu(acc+bias)->bf16 ; 2 = y=acc+bias+res(bf16) -> f32 + BN partials ;
//      3 = qkv head-scatter bf16
template<int EPI>
__global__ __launch_bounds__(512, 1)
void gemm_bt(const u16* __restrict__ A, const u16* __restrict__ W,
             const float* __restrict__ bias, u16* __restrict__ obf,
             float* __restrict__ of32, const u16* __restrict__ res,
             float* __restrict__ p1, float* __restrict__ p2,
             int M, int N, int K, int Nt, int TPB)
{
  __shared__ __align__(16) char smem[163840];
  const int tid = threadIdx.x;
  const int w = tid >> 6, lane = tid & 63;
  const int wm = w >> 2, wn = w & 3;
  const int fr = lane & 15, fg = lane >> 4;
  const int fko = fg * 8;
  const int grid = gridDim.x;
  const int q8 = grid >> 3, r8 = grid & 7;
  const int xcd = blockIdx.x & 7, pos = blockIdx.x >> 3;
  const int start = xcd < r8 ? xcd * (q8 + 1) : r8 * (q8 + 1) + (xcd - r8) * q8;
  const int swz = start + pos;
  const int nt = K >> 6;
  const int tot = TPB * nt;
  const int l3 = lane >> 3;
  const int k16s = ((lane & 7) ^ l3) * 8;
  int rowAK[2][2], rowBK[2][2];
  #pragma unroll
  for (int mh = 0; mh < 2; mh++)
    #pragma unroll
    for (int j = 0; j < 2; j++)
      rowAK[mh][j] = (mh*64 + j*128 + w*8 + l3) * K;
  #pragma unroll
  for (int h = 0; h < 2; h++)
    #pragma unroll
    for (int j = 0; j < 2; j++)
      rowBK[h][j] = (h*128 + (w + j*8)*8 + l3) * K;

  // full-tile stage: A -> slot s (4 gl_lds/thread), B -> slot s (4 gl_lds)
  auto stA = [&](int s, int soff) {
    #pragma unroll
    for (int mh = 0; mh < 2; mh++) {
      char* d = smem + s*32768 + (mh*64 + w*8)*128;
      gl_lds16(A + (size_t)soff + rowAK[mh][0] + k16s, d);
      gl_lds16(A + (size_t)soff + rowAK[mh][1] + k16s, d + 16384);
    }
  };
  auto stB = [&](int s, int soff) {
    #pragma unroll
    for (int h = 0; h < 2; h++) {
      char* d = smem + 98304 + s*32768 + (h*128 + w*8)*128;
      gl_lds16(W + (size_t)soff + rowBK[h][0] + k16s, d);
      gl_lds16(W + (size_t)soff + rowBK[h][1] + k16s, d + 8192);
    }
  };
  const int axor = (fr & 7) << 4;
  auto rdA2 = [&](int s, int mh, int kh, int mf) -> short8 {
    const int row = wm*128 + mh*64 + mf*16 + fr;
    return *(const short8*)(smem + s*32768 + row*128 + (((kh*32 + fko)*2) ^ axor));
  };
  auto rdB2 = [&](int s, int kh, int nf) -> short8 {
    const int row = wn*64 + nf*16 + fr;
    return *(const short8*)(smem + 98304 + s*32768 + row*128 + (((kh*32 + fko)*2) ^ axor));
  };
  auto coord = [&](int r, int& bm, int& bn) {
    const int lin = swz * TPB + r;
    const int mI = lin / Nt;
    bm = mI * 256; bn = (lin - mI * Nt) * 256;
  };

  f32x4 acc[8][4] = {};

  auto epi = [&](int bm, int bn) {
    float bs[4] = {0,0,0,0}, bq[4] = {0,0,0,0};
    #pragma unroll
    for (int mi = 0; mi < 8; mi++) {
      #pragma unroll
      for (int ni = 0; ni < 4; ni++) {
        const int c = bn + wn*64 + ni*16 + fr;
        const int r0 = bm + wm*128 + (mi>>2)*64 + (mi&3)*16 + fg*4;
        const float bc = bias[c];
        float v[4];
        #pragma unroll
        for (int j = 0; j < 4; j++) v[j] = acc[mi][ni][j] + bc;
        if constexpr (EPI == 1) {
          #pragma unroll
          for (int j = 0; j < 4; j++) v[j] = gelu_t(v[j]);
          const unsigned p01 = cvt_pk_bf16(v[0], v[1]);
          const unsigned p23 = cvt_pk_bf16(v[2], v[3]);
          u16* d = obf + (size_t)r0 * N + c;
          d[0] = (u16)p01; d[N] = (u16)(p01 >> 16);
          d[2*N] = (u16)p23; d[3*N] = (u16)(p23 >> 16);
        } else if constexpr (EPI == 2) {
          #pragma unroll
          for (int j = 0; j < 4; j++) {
            const float y = v[j] + bf2f(res[(size_t)(r0+j) * N + c]);
            of32[(size_t)(r0+j) * N + c] = y;
            bs[ni] += y; bq[ni] += y * y;
          }
        } else {
          const int which = c / DM;
          const int cc = c - which * DM;
          const int hh = cc >> 6, e = cc & 63;
          const int bb = r0 >> 7, l = r0 & 127;
          const unsigned p01 = cvt_pk_bf16(v[0], v[1]);
          const unsigned p23 = cvt_pk_bf16(v[2], v[3]);
          u16* d = obf + (size_t)which * QSZ + ((size_t)(bb*NH + hh) * SEQ + l) * HD + e;
          d[0] = (u16)p01; d[HD] = (u16)(p01 >> 16);
          d[2*HD] = (u16)p23; d[3*HD] = (u16)(p23 >> 16);
        }
        acc[mi][ni] = (f32x4){0.f, 0.f, 0.f, 0.f};
      }
    }
    if constexpr (EPI == 2) {
      const int mIdx = bm >> 8;
      #pragma unroll
      for (int ni = 0; ni < 4; ni++) {
        float s = bs[ni], qq = bq[ni];
        s  += __shfl_xor(s, 16);  s  += __shfl_xor(s, 32);
        qq += __shfl_xor(qq, 16); qq += __shfl_xor(qq, 32);
        if (fg == 0) {
          const int c = bn + wn*64 + ni*16 + fr;
          p1[(mIdx*2 + wm) * N + c] = s;
          p2[(mIdx*2 + wm) * N + c] = qq;
        }
      }
    }
  };

  // trackers: t (compute/epilogue), t+1 (B staging), t+2 (A staging)
  int r0t = 0, kt0 = 0, bm0, bn0; coord(0, bm0, bn0);
  int r1 = 0, kt1 = 1, bm1 = bm0, bn1 = bn0;
  int r2 = 0, kt2 = 2, bm2 = bm0;
  if (kt2 >= nt) { kt2 -= nt; r2 = 1; int d; if (r2 < TPB) coord(r2, bm2, d); }

  // prologue: A(0)->slot0, B(0)->slot0, A(1)->slot1. Queue: A0,B0,A1.
  stA(0, bm0*K + kt0*64);
  stB(0, bn0*K + kt0*64);
  if (tot > 1) stA(1, bm1*K + kt1*64);
  asm volatile("s_waitcnt vmcnt(4)" ::: "memory");   // A0,B0 landed; A1 in flight
  __builtin_amdgcn_s_barrier();

  short8 a0[4], a1[4], bk0[4], bk1[4];
  int bufA = 0;
  for (int it = 0; it < tot; ++it) {
    const int bufB = it & 1;
    int slA2 = bufA + 2; if (slA2 >= 3) slA2 -= 3;   // (it+2)%3
    const int slB1 = bufB ^ 1;
    const bool st1 = (it + 1 < tot), st2 = (it + 2 < tot);
    const int sB1 = bn1*K + kt1*64;
    const int sA2 = bm2*K + kt2*64;
    // ---- reads for mh0 + B (16 x b128) ----
    #pragma unroll
    for (int i = 0; i < 4; i++) a0[i] = rdA2(bufA, 0, 0, i);
    #pragma unroll
    for (int i = 0; i < 4; i++) a1[i] = rdA2(bufA, 0, 1, i);
    #pragma unroll
    for (int i = 0; i < 4; i++) bk0[i] = rdB2(bufB, 0, i);
    #pragma unroll
    for (int i = 0; i < 4; i++) bk1[i] = rdB2(bufB, 1, i);
    // ---- staging: B(t+1) FIRST, then A(t+2) (FIFO order for vmcnt) ----
    if (st1) stB(slB1, sB1);
    if (st2) stA(slA2, sA2);
    asm volatile("s_waitcnt lgkmcnt(0)" ::: "memory");
    __builtin_amdgcn_sched_barrier(0);
    __builtin_amdgcn_s_setprio(1);
    #pragma unroll
    for (int mi = 0; mi < 4; mi++)
      #pragma unroll
      for (int ni = 0; ni < 4; ni++)
        acc[mi][ni] = __builtin_amdgcn_mfma_f32_16x16x32_bf16(a0[mi], bk0[ni], acc[mi][ni], 0, 0, 0);
    #pragma unroll
    for (int mi = 0; mi < 4; mi++)
      #pragma unroll
      for (int ni = 0; ni < 4; ni++)
        acc[mi][ni] = __builtin_amdgcn_mfma_f32_16x16x32_bf16(a1[mi], bk1[ni], acc[mi][ni], 0, 0, 0);
    __builtin_amdgcn_s_setprio(0);
    // ---- reads for mh1 (8 x b128) — no barrier needed, same slot ----
    #pragma unroll
    for (int i = 0; i < 4; i++) a0[i] = rdA2(bufA, 1, 0, i);
    #pragma unroll
    for (int i = 0; i < 4; i++) a1[i] = rdA2(bufA, 1, 1, i);
    asm volatile("s_waitcnt lgkmcnt(0)" ::: "memory");
    __builtin_amdgcn_sched_barrier(0);
    __builtin_amdgcn_s_setprio(1);
    #pragma unroll
    for (int mi = 0; mi < 4; mi++)
      #pragma unroll
      for (int ni = 0; ni < 4; ni++)
        acc[4+mi][ni] = __builtin_amdgcn_mfma_f32_16x16x32_bf16(a0[mi], bk0[ni], acc[4+mi][ni], 0, 0, 0);
    #pragma unroll
    for (int mi = 0; mi < 4; mi++)
      #pragma unroll
      for (int ni = 0; ni < 4; ni++)
        acc[4+mi][ni] = __builtin_amdgcn_mfma_f32_16x16x32_bf16(a1[mi], bk1[ni], acc[4+mi][ni], 0, 0, 0);
    __builtin_amdgcn_s_setprio(0);
    // ---- single end-of-iter sync ----
    if (st2)      { asm volatile("s_waitcnt vmcnt(4)" ::: "memory"); }  // A(t+1),B(t+1) landed
    else if (st1) { asm volatile("s_waitcnt vmcnt(0)" ::: "memory"); }
    __builtin_amdgcn_s_barrier();
    // tile boundary: epilogue after the sync (stores retire over next iters)
    if (kt0 == nt - 1) {
      epi(bm0, bn0);
      kt0 = 0; r0t++;
      if (r0t < TPB) coord(r0t, bm0, bn0);
    } else kt0++;
    kt1++; if (kt1 == nt) { kt1 = 0; r1++; if (r1 < TPB) coord(r1, bm1, bn1); }
    kt2++; if (kt2 == nt) { kt2 = 0; r2++; if (r2 < TPB) { int d; coord(r2, bm2, d); } }
    bufA++; if (bufA == 3) bufA = 0;
  }
}

// ---------------- Attention: one block per (b,h) -----------------------------
__global__ __launch_bounds__(256)
void attn_kernel(const u16* __restrict__ qkvb, const u16* __restrict__ biasT,
                 u16* __restrict__ ab)
{
  const int h = blockIdx.x, b = blockIdx.y;
  const int tid = threadIdx.x, w = tid >> 6, lane = tid & 63;
  const int bh = b * NH + h;
  const u16* qp = qkvb + (size_t)bh * SEQ * HD;
  const u16* kp = qkvb + QSZ + (size_t)bh * SEQ * HD;
  const u16* vp = qkvb + 2 * QSZ + (size_t)bh * SEQ * HD;
  __shared__ __align__(16) u16 vT[HD * 136];
  __shared__ __align__(16) u16 P[SEQ * 136];
  {
    const int s = tid & 127, half = tid >> 7;
    #pragma unroll
    for (int rr = 0; rr < 4; rr++) {
      const int e0 = half * 32 + rr * 8;
      short8 v8 = *(const short8*)&vp[s * HD + e0];
      #pragma unroll
      for (int j = 0; j < 8; j++) vT[(e0 + j) * 136 + s] = (u16)v8[j];
    }
  }
  const int fr = lane & 15, fg = lane >> 4;
  f32x4 sacc[2][8] = {};
  #pragma unroll
  for (int ks = 0; ks < 2; ks++) {
    const int k0 = ks * 32 + fg * 8;
    short8 qf[2], kf[8];
    #pragma unroll
    for (int mi = 0; mi < 2; mi++) qf[mi] = *(const short8*)&qp[(w*32 + mi*16 + fr) * HD + k0];
    #pragma unroll
    for (int ni = 0; ni < 8; ni++) kf[ni] = *(const short8*)&kp[(ni*16 + fr) * HD + k0];
    #pragma unroll
    for (int mi = 0; mi < 2; mi++)
      #pragma unroll
      for (int ni = 0; ni < 8; ni++)
        sacc[mi][ni] = __builtin_amdgcn_mfma_f32_16x16x32_bf16(qf[mi], kf[ni], sacc[mi][ni], 0, 0, 0);
  }
  const u16* bt = biasT + (size_t)bh * SEQ * SEQ;
  #pragma unroll
  for (int mi = 0; mi < 2; mi++) {
    #pragma unroll
    for (int j = 0; j < 4; j++) {
      const int l = w*32 + mi*16 + fg*4 + j;
      float vals[8];
      float mx = -1e30f;
      #pragma unroll
      for (int ni = 0; ni < 8; ni++) {
        vals[ni] = sacc[mi][ni][j] * 0.125f + bf2f(bt[l * SEQ + ni*16 + fr]);
        mx = fmaxf(mx, vals[ni]);
      }
      #pragma unroll
      for (int d = 1; d < 16; d <<= 1) mx = fmaxf(mx, __shfl_xor(mx, d));
      float sum = 0.f;
      #pragma unroll
      for (int ni = 0; ni < 8; ni++) { vals[ni] = __expf(vals[ni] - mx); sum += vals[ni]; }
      #pragma unroll
      for (int d = 1; d < 16; d <<= 1) sum += __shfl_xor(sum, d);
      const float inv = 1.0f / sum;
      #pragma unroll
      for (int ni = 0; ni < 8; ni++) P[l * 136 + ni*16 + fr] = f2bf(vals[ni] * inv);
    }
  }
  __syncthreads();
  f32x4 oacc[2][4] = {};
  #pragma unroll
  for (int ss = 0; ss < 4; ss++) {
    const int s0 = ss * 32 + fg * 8;
    short8 pf[2], vf[4];
    #pragma unroll
    for (int mi = 0; mi < 2; mi++) pf[mi] = *(const short8*)&P[(w*32 + mi*16 + fr) * 136 + s0];
    #pragma unroll
    for (int ei = 0; ei < 4; ei++) vf[ei] = *(const short8*)&vT[(ei*16 + fr) * 136 + s0];
    #pragma unroll
    for (int mi = 0; mi < 2; mi++)
      #pragma unroll
      for (int ei = 0; ei < 4; ei++)
        oacc[mi][ei] = __builtin_amdgcn_mfma_f32_16x16x32_bf16(pf[mi], vf[ei], oacc[mi][ei], 0, 0, 0);
  }
  #pragma unroll
  for (int mi = 0; mi < 2; mi++)
    #pragma unroll
    for (int ei = 0; ei < 4; ei++)
      #pragma unroll
      for (int j = 0; j < 4; j++) {
        const int r = b * SEQ + w*32 + mi*16 + fg*4 + j;
        const int c = h * HD + ei*16 + fr;
        ab[(size_t)r * DM + c] = f2bf(oacc[mi][ei][j]);
      }
}

// ---------------- BatchNorm finalize from fused partials ---------------------
template<bool FINAL>
__global__ __launch_bounds__(256)
void bn_final(const float* __restrict__ p1, const float* __restrict__ p2,
              const float* __restrict__ ga, const float* __restrict__ be,
              const float* __restrict__ gb, const float* __restrict__ beb,
              float* __restrict__ sc, float* __restrict__ sh)
{
  const int c = blockIdx.x * 256 + threadIdx.x;
  float s = 0, q = 0;
  for (int i = 0; i < 112; i++) { s += p1[i * DM + c]; q += p2[i * DM + c]; }
  const float mean = s * (1.0f / MTOK);
  const float var = q * (1.0f / MTOK) - mean * mean;
  const float rstd = rsqrtf(var + 1e-5f);
  if constexpr (!FINAL) {
    const float g = ga[c] * rstd;
    sc[c] = g;
    sh[c] = be[c] - mean * g;
  } else {
    const float sc2 = ga[c] * rstd;
    const float sh2 = be[c] - mean * sc2;
    const float varf = sc2 * sc2 * var;
    const float meanf = sc2 * mean + sh2;
    const float scf = gb[c] * rsqrtf(varf + 1e-5f);
    const float shf = beb[c] - meanf * scf;
    sc[c] = scf * sc2;
    sh[c] = scf * sh2 + shf;
  }
}

// MODE 0: write xb (bf16) only (intermediate); MODE 1: write out f32 (final)
// 8 floats per thread (G13 vectorization)
template<int MODE>
__global__ __launch_bounds__(256)
void bn_apply(const float* __restrict__ xi, const float* __restrict__ sc,
              const float* __restrict__ sh, float* __restrict__ xo, u16* __restrict__ xb)
{
  const int i = blockIdx.x * 256 + threadIdx.x;   // 8-float units, total MTOK*DM/8
  const int c0 = (i % (DM / 8)) * 2;              // in float4 units
  float4 v0 = ((const float4*)xi)[i*2];
  float4 v1 = ((const float4*)xi)[i*2 + 1];
  const float4 s0 = ((const float4*)sc)[c0];
  const float4 s1 = ((const float4*)sc)[c0 + 1];
  const float4 h0 = ((const float4*)sh)[c0];
  const float4 h1 = ((const float4*)sh)[c0 + 1];
  float y0x = __builtin_fmaf(v0.x, s0.x, h0.x), y0y = __builtin_fmaf(v0.y, s0.y, h0.y);
  float y0z = __builtin_fmaf(v0.z, s0.z, h0.z), y0w = __builtin_fmaf(v0.w, s0.w, h0.w);
  float y1x = __builtin_fmaf(v1.x, s1.x, h1.x), y1y = __builtin_fmaf(v1.y, s1.y, h1.y);
  float y1z = __builtin_fmaf(v1.z, s1.z, h1.z), y1w = __builtin_fmaf(v1.w, s1.w, h1.w);
  if constexpr (MODE == 1) {
    ((float4*)xo)[i*2]     = (float4){y0x, y0y, y0z, y0w};
    ((float4*)xo)[i*2 + 1] = (float4){y1x, y1y, y1z, y1w};
  } else {
    short8 r;
    unsigned pA = cvt_pk_bf16(y0x, y0y), pB = cvt_pk_bf16(y0z, y0w);
    unsigned pC = cvt_pk_bf16(y1x, y1y), pD = cvt_pk_bf16(y1z, y1w);
    r[0] = (short)(u16)pA; r[1] = (short)(u16)(pA >> 16);
    r[2] = (short)(u16)pB; r[3] = (short)(u16)(pB >> 16);
    r[4] = (short)(u16)pC; r[5] = (short)(u16)(pC >> 16);
    r[6] = (short)(u16)pD; r[7] = (short)(u16)(pD >> 16);
    *(short8*)&xb[(size_t)i * 8] = r;
  }
}

// ---------------- setup kernels ----------------------------------------------
// 8 floats per thread
__global__ __launch_bounds__(256)
void conv_bf16(const float* __restrict__ s, u16* __restrict__ d, int n8)
{
  const int i = blockIdx.x * 256 + threadIdx.x;
  if (i >= n8) return;
  float4 v0 = ((const float4*)s)[i*2];
  float4 v1 = ((const float4*)s)[i*2 + 1];
  short8 r;
  unsigned pA = cvt_pk_bf16(v0.x, v0.y), pB = cvt_pk_bf16(v0.z, v0.w);
  unsigned pC = cvt_pk_bf16(v1.x, v1.y), pD = cvt_pk_bf16(v1.z, v1.w);
  r[0] = (short)(u16)pA; r[1] = (short)(u16)(pA >> 16);
  r[2] = (short)(u16)pB; r[3] = (short)(u16)(pB >> 16);
  r[4] = (short)(u16)pC; r[5] = (short)(u16)(pC >> 16);
  r[6] = (short)(u16)pD; r[7] = (short)(u16)(pD >> 16);
  *(short8*)&d[(size_t)i * 8] = r;
}

__global__ __launch_bounds__(256)
void conv_qkvw(const float* __restrict__ wq, const float* __restrict__ wk,
               const float* __restrict__ wv, u16* __restrict__ d)
{
  const int i = blockIdx.x * 256 + threadIdx.x;   // 8-float units
  const int per = QKVN * DM / 8;
  const int l = i / per;
  const int rem = i - l * per;
  const int r = rem / (DM / 8);
  const int cv = rem - r * (DM / 8);
  const float* srcrow;
  if (r < DM)          srcrow = wq + ((size_t)l * DM + r) * DM;
  else if (r < 2 * DM) srcrow = wk + ((size_t)l * DM + (r - DM)) * DM;
  else                 srcrow = wv + ((size_t)l * DM + (r - 2 * DM)) * DM;
  float4 v0 = ((const float4*)srcrow)[cv*2];
  float4 v1 = ((const float4*)srcrow)[cv*2 + 1];
  short8 o;
  unsigned pA = cvt_pk_bf16(v0.x, v0.y), pB = cvt_pk_bf16(v0.z, v0.w);
  unsigned pC = cvt_pk_bf16(v1.x, v1.y), pD = cvt_pk_bf16(v1.z, v1.w);
  o[0] = (short)(u16)pA; o[1] = (short)(u16)(pA >> 16);
  o[2] = (short)(u16)pB; o[3] = (short)(u16)(pB >> 16);
  o[4] = (short)(u16)pC; o[5] = (short)(u16)(pC >> 16);
  o[6] = (short)(u16)pD; o[7] = (short)(u16)(pD >> 16);
  *(short8*)&d[(size_t)i * 8] = o;
}

__global__ __launch_bounds__(256)
void conv_bias_qkv(const float* __restrict__ bq, const float* __restrict__ bk,
                   const float* __restrict__ bv, float* __restrict__ d)
{
  const int i = blockIdx.x * 256 + threadIdx.x;
  const int l = i / QKVN;
  const int r = i - l * QKVN;
  float v;
  if (r < DM)          v = bq[l * DM + r];
  else if (r < 2 * DM) v = bk[l * DM + r - DM];
  else                 v = bv[l * DM + r - 2 * DM];
  d[i] = v;
}

__global__ __launch_bounds__(256)
void bias_tr(const float* __restrict__ src, u16* __restrict__ dst)
{
  const int l = blockIdx.x, b = blockIdx.y;
  __shared__ float row[SEQ * NH];
  const float* s = src + ((size_t)b * SEQ + l) * SEQ * NH;
  for (int i = threadIdx.x; i < SEQ * NH; i += 256) row[i] = s[i];
  __syncthreads();
  for (int i = threadIdx.x; i < SEQ * NH; i += 256) {
    const int h = i >> 7, ss = i & 127;
    dst[((size_t)(b * NH + h) * SEQ + l) * SEQ + ss] = f2bf(row[ss * NH + h]);
  }
}

// ---------------- launch -----------------------------------------------------
extern "C" void kernel_launch(void* const* d_in, const int* in_sizes, int n_in,
                              void* d_out, int out_size, void* d_ws, size_t ws_size,
                              hipStream_t stream)
{
  const float* x    = (const float*)d_in[0];
  const float* abia = (const float*)d_in[1];
  const float* Wq   = (const float*)d_in[2];
  const float* bq   = (const float*)d_in[3];
  const float* Wk   = (const float*)d_in[4];
  const float* bk   = (const float*)d_in[5];
  const float* Wv   = (const float*)d_in[6];
  const float* bv   = (const float*)d_in[7];
  const float* Wo   = (const float*)d_in[8];
  const float* bo   = (const float*)d_in[9];
  const float* W1   = (const float*)d_in[10];
  const float* b1   = (const float*)d_in[11];
  const float* W2   = (const float*)d_in[12];
  const float* b2   = (const float*)d_in[13];
  const float* g1   = (const float*)d_in[14];
  const float* be1  = (const float*)d_in[15];
  const float* g2   = (const float*)d_in[16];
  const float* be2  = (const float*)d_in[17];
  const float* gf   = (const float*)d_in[18];
  const float* bef  = (const float*)d_in[19];
  float* out = (float*)d_out;

  char* ws = (char*)d_ws;
  size_t off = 0;
  auto alloc = [&](size_t n) -> char* {
    char* p = ws + off;
    off = (off + n + 255) & ~(size_t)255;
    return p;
  };
  u16*  wqkv  = (u16*)alloc((size_t)3 * QKVN * DM * 2);
  u16*  wo    = (u16*)alloc((size_t)3 * DM * DM * 2);
  u16*  w1    = (u16*)alloc((size_t)3 * FF * DM * 2);
  u16*  w2    = (u16*)alloc((size_t)3 * DM * FF * 2);
  float* bqkv = (float*)alloc((size_t)3 * QKVN * 4);
  u16*  xb    = (u16*)alloc((size_t)MTOK * DM * 2);
  u16*  ab    = (u16*)alloc((size_t)MTOK * DM * 2);
  u16*  big   = (u16*)alloc((size_t)MTOK * FF * 2);
  u16*  biasT = (u16*)alloc((size_t)HEADTOT * SEQ * SEQ * 2);
  float* p1   = (float*)alloc((size_t)112 * DM * 4);
  float* p2   = (float*)alloc((size_t)112 * DM * 4);
  float* sc   = (float*)alloc(DM * 4);
  float* sh   = (float*)alloc(DM * 4);
  if (off > ws_size) return;

  conv_qkvw<<<2592, 256, 0, stream>>>(Wq, Wk, Wv, wqkv);
  conv_bf16<<<864, 256, 0, stream>>>(Wo, wo, 3 * DM * DM / 8);
  conv_bf16<<<3456, 256, 0, stream>>>(W1, w1, 3 * FF * DM / 8);
  conv_bf16<<<3456, 256, 0, stream>>>(W2, w2, 3 * DM * FF / 8);
  conv_bias_qkv<<<27, 256, 0, stream>>>(bq, bk, bv, bqkv);
  bias_tr<<<dim3(SEQ, NB), 256, 0, stream>>>(abia, biasT);
  conv_bf16<<<MTOK * DM / 8 / 256, 256, 0, stream>>>(x, xb, MTOK * DM / 8);

  auto gemm = [&](int epi, const u16* Ap, const u16* Wp, const float* bp,
                  u16* ob, float* o32, const u16* rs, int M, int N, int K) {
    const int Nt = N / 256;
    const int tiles = (M / 256) * Nt;
    const int tpb = (tiles + 255) / 256;
    const int grid = tiles / tpb;          // exact for all our shapes
    if (epi == 1)
      gemm_bt<1><<<grid, 512, 0, stream>>>(Ap, Wp, bp, ob, o32, rs, p1, p2, M, N, K, Nt, tpb);
    else if (epi == 2)
      gemm_bt<2><<<grid, 512, 0, stream>>>(Ap, Wp, bp, ob, o32, rs, p1, p2, M, N, K, Nt, tpb);
    else
      gemm_bt<3><<<grid, 512, 0, stream>>>(Ap, Wp, bp, ob, o32, rs, p1, p2, M, N, K, Nt, tpb);
  };

  for (int l = 0; l < NLAYER; l++) {
    gemm(3, xb, wqkv + (size_t)l * QKVN * DM, bqkv + l * QKVN, big, nullptr, nullptr,
         MTOK, QKVN, DM);
    attn_kernel<<<dim3(NH, NB), 256, 0, stream>>>(big, biasT, ab);
    gemm(2, ab, wo + (size_t)l * DM * DM, bo + l * DM, nullptr, out, xb,
         MTOK, DM, DM);
    bn_final<false><<<3, 256, 0, stream>>>(p1, p2, g1 + l * DM, be1 + l * DM,
                                           nullptr, nullptr, sc, sh);
    bn_apply<0><<<MTOK * DM / 8 / 256, 256, 0, stream>>>(out, sc, sh, nullptr, xb);
    gemm(1, xb, w1 + (size_t)l * FF * DM, b1 + l * FF, big, nullptr, nullptr,
         MTOK, FF, DM);
    gemm(2, big, w2 + (size_t)l * DM * FF, b2 + l * DM, nullptr, out, xb,
         MTOK, DM, FF);
    if (l < NLAYER - 1) {
      bn_final<false><<<3, 256, 0, stream>>>(p1, p2, g2 + l * DM, be2 + l * DM,
                                             nullptr, nullptr, sc, sh);
      bn_apply<0><<<MTOK * DM / 8 / 256, 256, 0, stream>>>(out, sc, sh, nullptr, xb);
    } else {
      bn_final<true><<<3, 256, 0, stream>>>(p1, p2, g2 + l * DM, be2 + l * DM,
                                            gf, bef, sc, sh);
      bn_apply<1><<<MTOK * DM / 8 / 256, 256, 0, stream>>>(out, sc, sh, out, nullptr);
    }
  }
}